// Round 9
// baseline (157.443 us; speedup 1.0000x reference)
//
#include <hip/hip_runtime.h>
#include <hip/hip_bf16.h>
#include <math.h>

#define BB 4
#define CC 256
#define DKK 32
#define NN 4096
// 1/sqrt(32) * log2(e) — folded into q at QKV epilogue; attention uses exp2.
#define QSCALE 0.2550181864060454f

typedef __attribute__((ext_vector_type(8))) __bf16 bf16x8;
typedef __attribute__((ext_vector_type(4))) __bf16 bf16x4;
typedef __attribute__((ext_vector_type(4))) float f32x4;

// ---------------------------------------------------------------------------
// Kernel 1: FUSED x-transpose + QKV projection (was 2 kernels + HBM round-trip).
// Block: 64 n-cols x 320 o-rows, grid (64, B) = 256 blocks. 4 waves, wave w
// -> o 80w..80w+79.
// Stage: x fp32 (B,C,N) -> LDS fp32 tile -> transposed bf16 xsT[n][c]
// (4 rounds of 64 c). W stays fp32 in global; A-frags are converted
// fp32->bf16 in-register per K-step (depth-1 prefetched, L2-hot).
// Outputs: q,k (B,N,32) bf16 (q pre-scaled); V TILED [chunk n/32][c/16][16][32].
// ---------------------------------------------------------------------------
#define XST 260      // xsT row stride (bf16): 520B -> 130 dw == 2 mod 32 (2-way)
#define SCRST 65     // q/k scratch row stride (fp32)

__global__ __launch_bounds__(256) void qkv_kernel(
    const float* __restrict__ x,
    const float* __restrict__ Wq, const float* __restrict__ bq,
    const float* __restrict__ Wk, const float* __restrict__ bk,
    const float* __restrict__ Wv, const float* __restrict__ bv,
    __bf16* __restrict__ qws, __bf16* __restrict__ kws, __bf16* __restrict__ vws)
{
    // [0, 33280)        xsT: 64 x XST bf16
    // [33280, 50688)    xs32: 64 x 68 fp32 (staging)  /  scr overlay: 64 x 65 fp32
    __shared__ __align__(16) unsigned char smem[50688];
    __bf16* xsT  = (__bf16*)smem;
    float*  xs32 = (float*)(smem + 33280);
    float*  scr  = (float*)(smem + 33280);

    const int tid = threadIdx.x;
    const int w   = tid >> 6;
    const int l   = tid & 63;
    const int l15 = l & 15;
    const int lq  = l >> 4;
    const int n0  = blockIdx.x * 64;
    const int b   = blockIdx.y;

    // ---- staging: 4 rounds of 64 c ----
    for (int cr = 0; cr < 4; cr++) {
#pragma unroll
        for (int p = 0; p < 4; p++) {
            int cc = p * 16 + (tid >> 4);
            int nf = (tid & 15) * 4;
            float4 v = *(const float4*)&x[((size_t)(b * CC + cr * 64 + cc)) * NN + n0 + nf];
            *(float4*)&xs32[cc * 68 + nf] = v;
        }
        __syncthreads();
        {
            int n = tid >> 2, cs = (tid & 3) * 16;
            bf16x4 t0, t1, t2, t3;
#pragma unroll
            for (int j = 0; j < 4; j++) {
                t0[j] = (__bf16)xs32[(cs + j)      * 68 + n];
                t1[j] = (__bf16)xs32[(cs + 4 + j)  * 68 + n];
                t2[j] = (__bf16)xs32[(cs + 8 + j)  * 68 + n];
                t3[j] = (__bf16)xs32[(cs + 12 + j) * 68 + n];
            }
            *(bf16x4*)&xsT[n * XST + cr * 64 + cs]      = t0;
            *(bf16x4*)&xsT[n * XST + cr * 64 + cs + 4]  = t1;
            *(bf16x4*)&xsT[n * XST + cr * 64 + cs + 8]  = t2;
            *(bf16x4*)&xsT[n * XST + cr * 64 + cs + 12] = t3;
        }
        __syncthreads();
    }

    // ---- W row pointers per (w, ot): each 16-tile uses one matrix uniformly ----
    const float* wp[5];
#pragma unroll
    for (int ot = 0; ot < 5; ot++) {
        int ob = 80 * w + 16 * ot;
        const float* src = (ob < 32) ? (Wq + (size_t)ob * CC)
                         : (ob < 64) ? (Wk + (size_t)(ob - 32) * CC)
                                     : (Wv + (size_t)(ob - 64) * CC);
        wp[ot] = src + (size_t)l15 * CC;
    }

    const f32x4 zf = {0.f, 0.f, 0.f, 0.f};
    f32x4 acc[5][4];
#pragma unroll
    for (int i = 0; i < 5; i++)
#pragma unroll
        for (int j = 0; j < 4; j++) acc[i][j] = zf;

    // ---- MFMA loop: A from W fp32 (depth-1 prefetch + in-reg cvt), B from LDS ----
    float4 wc[5][2], wn[5][2];
#pragma unroll
    for (int ot = 0; ot < 5; ot++) {
        wc[ot][0] = *(const float4*)(wp[ot] + lq * 8);
        wc[ot][1] = *(const float4*)(wp[ot] + lq * 8 + 4);
    }
#pragma unroll
    for (int ks = 0; ks < 8; ks++) {
        if (ks < 7) {
#pragma unroll
            for (int ot = 0; ot < 5; ot++) {
                wn[ot][0] = *(const float4*)(wp[ot] + (ks + 1) * 32 + lq * 8);
                wn[ot][1] = *(const float4*)(wp[ot] + (ks + 1) * 32 + lq * 8 + 4);
            }
        }
        bf16x8 bfr[4];
#pragma unroll
        for (int nt = 0; nt < 4; nt++) {
            bf16x4 lo = *(const bf16x4*)&xsT[(nt * 16 + l15) * XST + ks * 32 + lq * 8];
            bf16x4 hi = *(const bf16x4*)&xsT[(nt * 16 + l15) * XST + ks * 32 + lq * 8 + 4];
            bfr[nt] = __builtin_shufflevector(lo, hi, 0, 1, 2, 3, 4, 5, 6, 7);
        }
#pragma unroll
        for (int ot = 0; ot < 5; ot++) {
            bf16x8 af;
            af[0] = (__bf16)wc[ot][0].x; af[1] = (__bf16)wc[ot][0].y;
            af[2] = (__bf16)wc[ot][0].z; af[3] = (__bf16)wc[ot][0].w;
            af[4] = (__bf16)wc[ot][1].x; af[5] = (__bf16)wc[ot][1].y;
            af[6] = (__bf16)wc[ot][1].z; af[7] = (__bf16)wc[ot][1].w;
#pragma unroll
            for (int nt = 0; nt < 4; nt++)
                acc[ot][nt] = __builtin_amdgcn_mfma_f32_16x16x32_bf16(af, bfr[nt], acc[ot][nt], 0, 0, 0);
        }
        if (ks < 7) {
#pragma unroll
            for (int ot = 0; ot < 5; ot++) { wc[ot][0] = wn[ot][0]; wc[ot][1] = wn[ot][1]; }
        }
    }

    // ---- epilogue: D row o = 80w + ot*16 + lq*4 + r, col n = nt*16 + l15 ----
    __syncthreads();   // xs32 done; scr overlay becomes safe to write
    const size_t vbase = (size_t)b * CC * NN;
#pragma unroll
    for (int ot = 0; ot < 5; ot++) {
        int ob = 80 * w + ot * 16;
#pragma unroll
        for (int nt = 0; nt < 4; nt++) {
#pragma unroll
            for (int r = 0; r < 4; r++) {
                int o = ob + lq * 4 + r;
                int n = nt * 16 + l15;
                float val = acc[ot][nt][r];
                if (ob >= 64) {
                    int c = o - 64;
                    int chunk = (n0 >> 5) + (nt >> 1);
                    vws[vbase + (size_t)chunk * 8192 + (5 * w - 4 + ot) * 512
                        + (lq * 4 + r) * 32 + (nt & 1) * 16 + l15] = (__bf16)(val + bv[c]);
                } else if (ob < 32) {
                    scr[o * SCRST + n] = (val + bq[o]) * QSCALE;
                } else {
                    scr[o * SCRST + n] = val + bk[o - 32];
                }
            }
        }
    }
    __syncthreads();
    {
        int n  = tid >> 2;            // 0..63
        int d0 = (tid & 3) * 8;       // 0,8,16,24
        bf16x8 qv, kv;
#pragma unroll
        for (int j = 0; j < 8; j++) {
            qv[j] = (__bf16)scr[(d0 + j) * SCRST + n];
            kv[j] = (__bf16)scr[(32 + d0 + j) * SCRST + n];
        }
        size_t base = ((size_t)b * NN + n0 + n) * DKK + d0;
        *(bf16x8*)&qws[base] = qv;
        *(bf16x8*)&kws[base] = kv;
    }
}

// ---------------------------------------------------------------------------
// Kernel 2: flash attention — n-split waves, zero-barrier main loop,
// 64m x 128c blocks, grid 512 (2 blocks/CU = 2 waves/SIMD). Wave w owns
// n-chunk (ic*4+w)*32: computes its own P (8 KQ MFMA + 32 exp2), round-trips
// through WAVE-PRIVATE LDS (PST=36 -> 16-distinct-bank rows, b64 ops),
// then PV over the block's 128-c half. exp2 is raw v_exp_f32 (scale+log2e
// pre-folded into q). acc[4][8]=128 AGPRs; ~250 regs/wave = 2 waves/SIMD.
// ---------------------------------------------------------------------------
#define PST 36                     // P row stride (bf16): 72B rows
#define MST 68                     // O-reduce row stride (dwords)
#define PWSZ (64 * PST)            // one P buffer (elems)

__global__ __launch_bounds__(256, 2) void attn_kernel(
    const __bf16* __restrict__ qb, const __bf16* __restrict__ kb,
    const __bf16* __restrict__ vt, const float* __restrict__ x,
    float* __restrict__ out)
{
    // [0, 36864)      pbuf: 4 waves x 2 bufs x 64 x PST bf16
    // [0, 34816)      Ored overlay (epilogue): 4 waves x 32 x MST fp32
    // [36864, 37888)  Ls[4][64]
    // [37888, 38144)  Linv[64]
    __shared__ __align__(16) unsigned char smem[38144];
    __bf16* pw   = (__bf16*)smem + (threadIdx.x >> 6) * 2 * PWSZ;
    float*  Ls   = (float*)(smem + 36864);
    float*  Linv = (float*)(smem + 37888);

    const int tid = threadIdx.x;
    const int w   = tid >> 6;
    const int l   = tid & 63;
    const int l15 = l & 15;
    const int lq  = l >> 4;

    // XCD swizzle: batch pinned to an XCD pair -> K/V/Q stay L2-resident
    const int beta = blockIdx.x;
    const int b    = (beta >> 1) & 3;
    const int ch   = (beta >> 3) & 1;                        // c-half
    const int mt   = ((beta >> 4) << 1) | (beta & 1);        // 0..63
    const int m0   = mt * 64;

    const __bf16* qbb = qb + (size_t)b * NN * DKK;
    const __bf16* kbb = kb + (size_t)b * NN * DKK;
    const __bf16* vtb = vt + (size_t)b * CC * NN;

    bf16x8 qa[4];
#pragma unroll
    for (int af = 0; af < 4; af++)
        qa[af] = *(const bf16x8*)(qbb + (size_t)(m0 + af * 16 + l15) * DKK + lq * 8);

    const __bf16* kstrip = kbb + (size_t)(w * 32 + l15) * DKK + lq * 8;     // + ic*128*DKK
    const __bf16* vstrip = vtb + (size_t)w * 8192 + (size_t)ch * 4096
                               + l15 * 32 + lq * 8;                          // + ic*32768 + ct*512

    const f32x4 zf = {0.f, 0.f, 0.f, 0.f};
    f32x4 acc[4][8];
#pragma unroll
    for (int i = 0; i < 4; i++)
#pragma unroll
        for (int j = 0; j < 8; j++) acc[i][j] = zf;
    float lacc[4] = {0.f, 0.f, 0.f, 0.f};

    // ---- prologue: P(0) -> buf 0; prefetch k(1) ----
    bf16x8 kA0 = *(const bf16x8*)kstrip;
    bf16x8 kA1 = *(const bf16x8*)(kstrip + 16 * DKK);
#pragma unroll
    for (int af = 0; af < 4; af++) {
        f32x4 e0 = __builtin_amdgcn_mfma_f32_16x16x32_bf16(kA0, qa[af], zf, 0, 0, 0);
        f32x4 e1 = __builtin_amdgcn_mfma_f32_16x16x32_bf16(kA1, qa[af], zf, 0, 0, 0);
        bf16x4 p0, p1;
#pragma unroll
        for (int r = 0; r < 4; r++) {
            float v0 = __builtin_amdgcn_exp2f(e0[r]); lacc[af] += v0; p0[r] = (__bf16)v0;
            float v1 = __builtin_amdgcn_exp2f(e1[r]); lacc[af] += v1; p1[r] = (__bf16)v1;
        }
        *(bf16x4*)&pw[(af * 16 + l15) * PST + lq * 4]      = p0;
        *(bf16x4*)&pw[(af * 16 + l15) * PST + 16 + lq * 4] = p1;
    }
    kA0 = *(const bf16x8*)(kstrip + (size_t)128 * DKK);
    kA1 = *(const bf16x8*)(kstrip + (size_t)144 * DKK);

    // ---- main loop: zero barriers, purely intra-wave ----
#pragma unroll 2
    for (int ic = 0; ic < 31; ic++) {
        const int cur = ic & 1;
        const __bf16* vch = vstrip + (size_t)ic * 32768;

        bf16x8 vfC[4], vfN[4];
#pragma unroll
        for (int ct = 0; ct < 4; ct++)
            vfC[ct] = *(const bf16x8*)(vch + ct * 512);

        bf16x8 pf[4];
#pragma unroll
        for (int af = 0; af < 4; af++) {
            bf16x4 plo = *(const bf16x4*)&pw[cur * PWSZ + (af * 16 + l15) * PST + lq * 8];
            bf16x4 phi = *(const bf16x4*)&pw[cur * PWSZ + (af * 16 + l15) * PST + lq * 8 + 4];
            pf[af] = __builtin_shufflevector(plo, phi, 0, 1, 2, 3, 4, 5, 6, 7);
        }

        // KQ(ic+1) + exp2 into the other wave-private buffer
#pragma unroll
        for (int af = 0; af < 4; af++) {
            f32x4 e0 = __builtin_amdgcn_mfma_f32_16x16x32_bf16(kA0, qa[af], zf, 0, 0, 0);
            f32x4 e1 = __builtin_amdgcn_mfma_f32_16x16x32_bf16(kA1, qa[af], zf, 0, 0, 0);
            bf16x4 p0, p1;
#pragma unroll
            for (int r = 0; r < 4; r++) {
                float v0 = __builtin_amdgcn_exp2f(e0[r]); lacc[af] += v0; p0[r] = (__bf16)v0;
                float v1 = __builtin_amdgcn_exp2f(e1[r]); lacc[af] += v1; p1[r] = (__bf16)v1;
            }
            *(bf16x4*)&pw[(cur ^ 1) * PWSZ + (af * 16 + l15) * PST + lq * 4]      = p0;
            *(bf16x4*)&pw[(cur ^ 1) * PWSZ + (af * 16 + l15) * PST + 16 + lq * 4] = p1;
        }
        // prefetch k(ic+2) (OOB at tail lands in adjacent ws region — unused)
        kA0 = *(const bf16x8*)(kstrip + (size_t)(ic + 2) * 128 * DKK);
        kA1 = *(const bf16x8*)(kstrip + (size_t)((ic + 2) * 128 + 16) * DKK);

        // PV(ic): 2 c-groups of 4 tiles
#pragma unroll
        for (int ct = 0; ct < 4; ct++)
            vfN[ct] = *(const bf16x8*)(vch + (4 + ct) * 512);
#pragma unroll
        for (int ct = 0; ct < 4; ct++)
#pragma unroll
            for (int af = 0; af < 4; af++)
                acc[af][ct] = __builtin_amdgcn_mfma_f32_16x16x32_bf16(vfC[ct], pf[af], acc[af][ct], 0, 0, 0);
#pragma unroll
        for (int ct = 0; ct < 4; ct++)
#pragma unroll
            for (int af = 0; af < 4; af++)
                acc[af][4 + ct] = __builtin_amdgcn_mfma_f32_16x16x32_bf16(vfN[ct], pf[af], acc[af][4 + ct], 0, 0, 0);
    }

    // ---- peel: PV(31) ----
    {
        const __bf16* vch = vstrip + (size_t)31 * 32768;
        bf16x8 pf[4];
#pragma unroll
        for (int af = 0; af < 4; af++) {
            bf16x4 plo = *(const bf16x4*)&pw[(31 & 1) * PWSZ + (af * 16 + l15) * PST + lq * 8];
            bf16x4 phi = *(const bf16x4*)&pw[(31 & 1) * PWSZ + (af * 16 + l15) * PST + lq * 8 + 4];
            pf[af] = __builtin_shufflevector(plo, phi, 0, 1, 2, 3, 4, 5, 6, 7);
        }
        bf16x8 vfC[4], vfN[4];
#pragma unroll
        for (int ct = 0; ct < 4; ct++) vfC[ct] = *(const bf16x8*)(vch + ct * 512);
#pragma unroll
        for (int ct = 0; ct < 4; ct++) vfN[ct] = *(const bf16x8*)(vch + (4 + ct) * 512);
#pragma unroll
        for (int ct = 0; ct < 4; ct++)
#pragma unroll
            for (int af = 0; af < 4; af++)
                acc[af][ct] = __builtin_amdgcn_mfma_f32_16x16x32_bf16(vfC[ct], pf[af], acc[af][ct], 0, 0, 0);
#pragma unroll
        for (int ct = 0; ct < 4; ct++)
#pragma unroll
            for (int af = 0; af < 4; af++)
                acc[af][4 + ct] = __builtin_amdgcn_mfma_f32_16x16x32_bf16(vfN[ct], pf[af], acc[af][4 + ct], 0, 0, 0);
    }

    // ---- l: intra-wave reduce, publish per-wave partials ----
#pragma unroll
    for (int af = 0; af < 4; af++) {
        lacc[af] += __shfl_xor(lacc[af], 16, 64);
        lacc[af] += __shfl_xor(lacc[af], 32, 64);
    }
    if (lq == 0) {
#pragma unroll
        for (int af = 0; af < 4; af++) Ls[w * 64 + af * 16 + l15] = lacc[af];
    }
    __syncthreads();
    if (tid < 64)
        Linv[tid] = 1.0f / (Ls[tid] + Ls[64 + tid] + Ls[128 + tid] + Ls[192 + tid]);

    // ---- epilogue: cross-wave O reduce in 4 quarters of 32 c ----
    float* Ored = (float*)smem + w * (32 * MST);
#pragma unroll
    for (int q = 0; q < 4; q++) {
        if (q > 0) __syncthreads();       // prior quarter's reads done
#pragma unroll
        for (int ctp = 0; ctp < 2; ctp++) {
            int ct = 2 * q + ctp;
#pragma unroll
            for (int af = 0; af < 4; af++) {
#pragma unroll
                for (int r = 0; r < 4; r++)
                    Ored[(ctp * 16 + lq * 4 + r) * MST + af * 16 + l15] = acc[af][ct][r];
            }
        }
        __syncthreads();
        const int cl  = tid >> 3;         // 0..31 (c within quarter)
        const int mi0 = (tid & 7) * 8;    // m offset
        const float* Ob = (const float*)smem + cl * MST;
#pragma unroll
        for (int j = 0; j < 2; j++) {
            int mi = mi0 + 4 * j;
            f32x4 s = *(const f32x4*)&Ob[mi];
            s = s + *(const f32x4*)&Ob[1 * (32 * MST) + mi];
            s = s + *(const f32x4*)&Ob[2 * (32 * MST) + mi];
            s = s + *(const f32x4*)&Ob[3 * (32 * MST) + mi];
            f32x4 li = *(const f32x4*)&Linv[mi];
            int c = ch * 128 + q * 32 + cl;
            size_t gi = ((size_t)(b * CC + c)) * NN + m0 + mi;
            f32x4 xr = *(const f32x4*)&x[gi];
            *(f32x4*)&out[gi] = s * li + xr;
        }
    }
}

extern "C" void kernel_launch(void* const* d_in, const int* in_sizes, int n_in,
                              void* d_out, int out_size, void* d_ws, size_t ws_size,
                              hipStream_t stream) {
    const float* x  = (const float*)d_in[0];
    const float* Wq = (const float*)d_in[1];
    const float* bq = (const float*)d_in[2];
    const float* Wk = (const float*)d_in[3];
    const float* bk = (const float*)d_in[4];
    const float* Wv = (const float*)d_in[5];
    const float* bv = (const float*)d_in[6];
    float* out = (float*)d_out;

    __bf16* qws = (__bf16*)d_ws;                       // B*N*32
    __bf16* kws = qws + (size_t)BB * NN * DKK;         // B*N*32
    __bf16* vws = kws + (size_t)BB * NN * DKK;         // B*C*N (tiled)

    qkv_kernel<<<dim3(64, BB), 256, 0, stream>>>(x, Wq, bq, Wk, bk, Wv, bv,
                                                 qws, kws, vws);
    attn_kernel<<<dim3(512), 256, 0, stream>>>(qws, kws, vws, x, out);
}

// Round 10
// 153.093 us; speedup vs baseline: 1.0284x; 1.0284x over previous
//
#include <hip/hip_runtime.h>
#include <hip/hip_bf16.h>
#include <math.h>

#define BB 4
#define CC 256
#define DKK 32
#define NN 4096
// 1/sqrt(32) * log2(e) — folded into q at QKV epilogue; attention uses exp2.
#define QSCALE 0.2550181864060454f

typedef __attribute__((ext_vector_type(8))) __bf16 bf16x8;
typedef __attribute__((ext_vector_type(4))) __bf16 bf16x4;
typedef __attribute__((ext_vector_type(4))) float f32x4;

// ---------------------------------------------------------------------------
// Kernel 1: fused x-transpose + QKV projection, throughput version.
// Block: 32 n x 320 o, grid (128, B) = 512 (2 blocks/CU). 4 waves, wave w ->
// o 80w..80w+79.
// Staging: x fp32 (B,C,N) -> bf16 xsT[n][c] via direct scalar ds_write_b16
// (uniform <=2-way banks), ONE barrier, no fp32 LDS intermediate, no serial
// rounds. W stays fp32 in global (L2-hot), converted in-register per K-step
// (depth-1 prefetch). Outputs: q,k (B,N,32) bf16 (q pre-scaled);
// V TILED [chunk n/32][c/16][16][32].
// ---------------------------------------------------------------------------
#define XST 260      // xsT row stride (bf16 elems)
#define SCRST 33     // q/k scratch row stride (fp32) -> 2-way banks both phases

__global__ __launch_bounds__(256, 2) void qkv_kernel(
    const float* __restrict__ x,
    const float* __restrict__ Wq, const float* __restrict__ bq,
    const float* __restrict__ Wk, const float* __restrict__ bk,
    const float* __restrict__ Wv, const float* __restrict__ bv,
    __bf16* __restrict__ qws, __bf16* __restrict__ kws, __bf16* __restrict__ vws)
{
    // [0, 16640)  xsT: 32 x XST bf16   (main loop)
    // [0, 8448)   scr overlay: 64 x SCRST fp32 (epilogue, after barrier)
    __shared__ __align__(16) unsigned char smem[16640];
    __bf16* xsT = (__bf16*)smem;
    float*  scr = (float*)smem;

    const int tid = threadIdx.x;
    const int w   = tid >> 6;
    const int l   = tid & 63;
    const int l15 = l & 15;
    const int lq  = l >> 4;
    const int n0  = blockIdx.x * 32;
    const int b   = blockIdx.y;

    // ---- staging: thread reads float4 (4 n, 1 c), writes 4 bf16 scalars ----
    {
        const int cb = tid >> 3;            // 0..31
        const int nf = (tid & 7) * 4;       // 0..28
        const float* xp = x + ((size_t)(b * CC) + cb) * NN + n0 + nf;
#pragma unroll
        for (int r = 0; r < 8; r++) {
            float4 v = *(const float4*)(xp + (size_t)r * 32 * NN);
            int c = r * 32 + cb;
            xsT[(nf + 0) * XST + c] = (__bf16)v.x;
            xsT[(nf + 1) * XST + c] = (__bf16)v.y;
            xsT[(nf + 2) * XST + c] = (__bf16)v.z;
            xsT[(nf + 3) * XST + c] = (__bf16)v.w;
        }
    }

    // ---- W row pointers per (w, ot): each 16-tile uses one matrix ----
    const float* wp[5];
#pragma unroll
    for (int ot = 0; ot < 5; ot++) {
        int ob = 80 * w + 16 * ot;
        const float* src = (ob < 32) ? (Wq + (size_t)ob * CC)
                         : (ob < 64) ? (Wk + (size_t)(ob - 32) * CC)
                                     : (Wv + (size_t)(ob - 64) * CC);
        wp[ot] = src + (size_t)l15 * CC;
    }

    // prefetch W k-step 0 (overlaps the LDS staging writes)
    float4 wc[5][2], wn[5][2];
#pragma unroll
    for (int ot = 0; ot < 5; ot++) {
        wc[ot][0] = *(const float4*)(wp[ot] + lq * 8);
        wc[ot][1] = *(const float4*)(wp[ot] + lq * 8 + 4);
    }

    __syncthreads();

    const f32x4 zf = {0.f, 0.f, 0.f, 0.f};
    f32x4 acc[5][2];
#pragma unroll
    for (int i = 0; i < 5; i++)
#pragma unroll
        for (int j = 0; j < 2; j++) acc[i][j] = zf;

    // ---- MFMA loop: A = W (in-reg fp32->bf16), B = xsT ----
#pragma unroll
    for (int ks = 0; ks < 8; ks++) {
        if (ks < 7) {
#pragma unroll
            for (int ot = 0; ot < 5; ot++) {
                wn[ot][0] = *(const float4*)(wp[ot] + (ks + 1) * 32 + lq * 8);
                wn[ot][1] = *(const float4*)(wp[ot] + (ks + 1) * 32 + lq * 8 + 4);
            }
        }
        bf16x8 bfr[2];
#pragma unroll
        for (int nt = 0; nt < 2; nt++) {
            bf16x4 lo = *(const bf16x4*)&xsT[(nt * 16 + l15) * XST + ks * 32 + lq * 8];
            bf16x4 hi = *(const bf16x4*)&xsT[(nt * 16 + l15) * XST + ks * 32 + lq * 8 + 4];
            bfr[nt] = __builtin_shufflevector(lo, hi, 0, 1, 2, 3, 4, 5, 6, 7);
        }
#pragma unroll
        for (int ot = 0; ot < 5; ot++) {
            bf16x8 af;
            af[0] = (__bf16)wc[ot][0].x; af[1] = (__bf16)wc[ot][0].y;
            af[2] = (__bf16)wc[ot][0].z; af[3] = (__bf16)wc[ot][0].w;
            af[4] = (__bf16)wc[ot][1].x; af[5] = (__bf16)wc[ot][1].y;
            af[6] = (__bf16)wc[ot][1].z; af[7] = (__bf16)wc[ot][1].w;
#pragma unroll
            for (int nt = 0; nt < 2; nt++)
                acc[ot][nt] = __builtin_amdgcn_mfma_f32_16x16x32_bf16(af, bfr[nt], acc[ot][nt], 0, 0, 0);
        }
        if (ks < 7) {
#pragma unroll
            for (int ot = 0; ot < 5; ot++) { wc[ot][0] = wn[ot][0]; wc[ot][1] = wn[ot][1]; }
        }
    }

    __syncthreads();   // xsT dead -> scr overlay safe

    // ---- epilogue: D row o = 80w + ot*16 + lq*4 + r, col n = nt*16 + l15 ----
    __bf16* vchunk = vws + (size_t)b * CC * NN + (size_t)(n0 >> 5) * 8192;
#pragma unroll
    for (int ot = 0; ot < 5; ot++) {
        int ob = 80 * w + ot * 16;
#pragma unroll
        for (int nt = 0; nt < 2; nt++) {
#pragma unroll
            for (int r = 0; r < 4; r++) {
                int o = ob + lq * 4 + r;
                int n = nt * 16 + l15;
                float val = acc[ot][nt][r];
                if (ob >= 64) {
                    int c = o - 64;
                    vchunk[(5 * w - 4 + ot) * 512 + (lq * 4 + r) * 32 + n] =
                        (__bf16)(val + bv[c]);
                } else if (ob < 32) {
                    scr[o * SCRST + n] = (val + bq[o]) * QSCALE;
                } else {
                    scr[o * SCRST + n] = val + bk[o - 32];
                }
            }
        }
    }
    __syncthreads();
    {
        int n  = tid >> 3;            // 0..31
        int d0 = (tid & 7) * 4;       // 0,4,..,28
        bf16x4 qv, kv;
#pragma unroll
        for (int j = 0; j < 4; j++) {
            qv[j] = (__bf16)scr[(d0 + j) * SCRST + n];
            kv[j] = (__bf16)scr[(32 + d0 + j) * SCRST + n];
        }
        size_t base = ((size_t)b * NN + n0 + n) * DKK + d0;
        *(bf16x4*)&qws[base] = qv;
        *(bf16x4*)&kws[base] = kv;
    }
}

// ---------------------------------------------------------------------------
// Kernel 2: flash attention — UNCHANGED from round 9 (clean A/B on qkv).
// n-split waves, zero-barrier main loop, 64m x 128c blocks, grid 512
// (2 blocks/CU = 2 waves/SIMD). PST=36; exp2 with scale+log2e folded into q.
// ---------------------------------------------------------------------------
#define PST 36                     // P row stride (bf16): 72B rows
#define MST 68                     // O-reduce row stride (dwords)
#define PWSZ (64 * PST)            // one P buffer (elems)

__global__ __launch_bounds__(256, 2) void attn_kernel(
    const __bf16* __restrict__ qb, const __bf16* __restrict__ kb,
    const __bf16* __restrict__ vt, const float* __restrict__ x,
    float* __restrict__ out)
{
    __shared__ __align__(16) unsigned char smem[38144];
    __bf16* pw   = (__bf16*)smem + (threadIdx.x >> 6) * 2 * PWSZ;
    float*  Ls   = (float*)(smem + 36864);
    float*  Linv = (float*)(smem + 37888);

    const int tid = threadIdx.x;
    const int w   = tid >> 6;
    const int l   = tid & 63;
    const int l15 = l & 15;
    const int lq  = l >> 4;

    const int beta = blockIdx.x;
    const int b    = (beta >> 1) & 3;
    const int ch   = (beta >> 3) & 1;
    const int mt   = ((beta >> 4) << 1) | (beta & 1);
    const int m0   = mt * 64;

    const __bf16* qbb = qb + (size_t)b * NN * DKK;
    const __bf16* kbb = kb + (size_t)b * NN * DKK;
    const __bf16* vtb = vt + (size_t)b * CC * NN;

    bf16x8 qa[4];
#pragma unroll
    for (int af = 0; af < 4; af++)
        qa[af] = *(const bf16x8*)(qbb + (size_t)(m0 + af * 16 + l15) * DKK + lq * 8);

    const __bf16* kstrip = kbb + (size_t)(w * 32 + l15) * DKK + lq * 8;
    const __bf16* vstrip = vtb + (size_t)w * 8192 + (size_t)ch * 4096
                               + l15 * 32 + lq * 8;

    const f32x4 zf = {0.f, 0.f, 0.f, 0.f};
    f32x4 acc[4][8];
#pragma unroll
    for (int i = 0; i < 4; i++)
#pragma unroll
        for (int j = 0; j < 8; j++) acc[i][j] = zf;
    float lacc[4] = {0.f, 0.f, 0.f, 0.f};

    bf16x8 kA0 = *(const bf16x8*)kstrip;
    bf16x8 kA1 = *(const bf16x8*)(kstrip + 16 * DKK);
#pragma unroll
    for (int af = 0; af < 4; af++) {
        f32x4 e0 = __builtin_amdgcn_mfma_f32_16x16x32_bf16(kA0, qa[af], zf, 0, 0, 0);
        f32x4 e1 = __builtin_amdgcn_mfma_f32_16x16x32_bf16(kA1, qa[af], zf, 0, 0, 0);
        bf16x4 p0, p1;
#pragma unroll
        for (int r = 0; r < 4; r++) {
            float v0 = __builtin_amdgcn_exp2f(e0[r]); lacc[af] += v0; p0[r] = (__bf16)v0;
            float v1 = __builtin_amdgcn_exp2f(e1[r]); lacc[af] += v1; p1[r] = (__bf16)v1;
        }
        *(bf16x4*)&pw[(af * 16 + l15) * PST + lq * 4]      = p0;
        *(bf16x4*)&pw[(af * 16 + l15) * PST + 16 + lq * 4] = p1;
    }
    kA0 = *(const bf16x8*)(kstrip + (size_t)128 * DKK);
    kA1 = *(const bf16x8*)(kstrip + (size_t)144 * DKK);

#pragma unroll 2
    for (int ic = 0; ic < 31; ic++) {
        const int cur = ic & 1;
        const __bf16* vch = vstrip + (size_t)ic * 32768;

        bf16x8 vfC[4], vfN[4];
#pragma unroll
        for (int ct = 0; ct < 4; ct++)
            vfC[ct] = *(const bf16x8*)(vch + ct * 512);

        bf16x8 pf[4];
#pragma unroll
        for (int af = 0; af < 4; af++) {
            bf16x4 plo = *(const bf16x4*)&pw[cur * PWSZ + (af * 16 + l15) * PST + lq * 8];
            bf16x4 phi = *(const bf16x4*)&pw[cur * PWSZ + (af * 16 + l15) * PST + lq * 8 + 4];
            pf[af] = __builtin_shufflevector(plo, phi, 0, 1, 2, 3, 4, 5, 6, 7);
        }

#pragma unroll
        for (int af = 0; af < 4; af++) {
            f32x4 e0 = __builtin_amdgcn_mfma_f32_16x16x32_bf16(kA0, qa[af], zf, 0, 0, 0);
            f32x4 e1 = __builtin_amdgcn_mfma_f32_16x16x32_bf16(kA1, qa[af], zf, 0, 0, 0);
            bf16x4 p0, p1;
#pragma unroll
            for (int r = 0; r < 4; r++) {
                float v0 = __builtin_amdgcn_exp2f(e0[r]); lacc[af] += v0; p0[r] = (__bf16)v0;
                float v1 = __builtin_amdgcn_exp2f(e1[r]); lacc[af] += v1; p1[r] = (__bf16)v1;
            }
            *(bf16x4*)&pw[(cur ^ 1) * PWSZ + (af * 16 + l15) * PST + lq * 4]      = p0;
            *(bf16x4*)&pw[(cur ^ 1) * PWSZ + (af * 16 + l15) * PST + 16 + lq * 4] = p1;
        }
        kA0 = *(const bf16x8*)(kstrip + (size_t)(ic + 2) * 128 * DKK);
        kA1 = *(const bf16x8*)(kstrip + (size_t)((ic + 2) * 128 + 16) * DKK);

#pragma unroll
        for (int ct = 0; ct < 4; ct++)
            vfN[ct] = *(const bf16x8*)(vch + (4 + ct) * 512);
#pragma unroll
        for (int ct = 0; ct < 4; ct++)
#pragma unroll
            for (int af = 0; af < 4; af++)
                acc[af][ct] = __builtin_amdgcn_mfma_f32_16x16x32_bf16(vfC[ct], pf[af], acc[af][ct], 0, 0, 0);
#pragma unroll
        for (int ct = 0; ct < 4; ct++)
#pragma unroll
            for (int af = 0; af < 4; af++)
                acc[af][4 + ct] = __builtin_amdgcn_mfma_f32_16x16x32_bf16(vfN[ct], pf[af], acc[af][4 + ct], 0, 0, 0);
    }

    {
        const __bf16* vch = vstrip + (size_t)31 * 32768;
        bf16x8 pf[4];
#pragma unroll
        for (int af = 0; af < 4; af++) {
            bf16x4 plo = *(const bf16x4*)&pw[(31 & 1) * PWSZ + (af * 16 + l15) * PST + lq * 8];
            bf16x4 phi = *(const bf16x4*)&pw[(31 & 1) * PWSZ + (af * 16 + l15) * PST + lq * 8 + 4];
            pf[af] = __builtin_shufflevector(plo, phi, 0, 1, 2, 3, 4, 5, 6, 7);
        }
        bf16x8 vfC[4], vfN[4];
#pragma unroll
        for (int ct = 0; ct < 4; ct++) vfC[ct] = *(const bf16x8*)(vch + ct * 512);
#pragma unroll
        for (int ct = 0; ct < 4; ct++) vfN[ct] = *(const bf16x8*)(vch + (4 + ct) * 512);
#pragma unroll
        for (int ct = 0; ct < 4; ct++)
#pragma unroll
            for (int af = 0; af < 4; af++)
                acc[af][ct] = __builtin_amdgcn_mfma_f32_16x16x32_bf16(vfC[ct], pf[af], acc[af][ct], 0, 0, 0);
#pragma unroll
        for (int ct = 0; ct < 4; ct++)
#pragma unroll
            for (int af = 0; af < 4; af++)
                acc[af][4 + ct] = __builtin_amdgcn_mfma_f32_16x16x32_bf16(vfN[ct], pf[af], acc[af][4 + ct], 0, 0, 0);
    }

#pragma unroll
    for (int af = 0; af < 4; af++) {
        lacc[af] += __shfl_xor(lacc[af], 16, 64);
        lacc[af] += __shfl_xor(lacc[af], 32, 64);
    }
    if (lq == 0) {
#pragma unroll
        for (int af = 0; af < 4; af++) Ls[w * 64 + af * 16 + l15] = lacc[af];
    }
    __syncthreads();
    if (tid < 64)
        Linv[tid] = 1.0f / (Ls[tid] + Ls[64 + tid] + Ls[128 + tid] + Ls[192 + tid]);

    float* Ored = (float*)smem + w * (32 * MST);
#pragma unroll
    for (int q = 0; q < 4; q++) {
        if (q > 0) __syncthreads();
#pragma unroll
        for (int ctp = 0; ctp < 2; ctp++) {
            int ct = 2 * q + ctp;
#pragma unroll
            for (int af = 0; af < 4; af++) {
#pragma unroll
                for (int r = 0; r < 4; r++)
                    Ored[(ctp * 16 + lq * 4 + r) * MST + af * 16 + l15] = acc[af][ct][r];
            }
        }
        __syncthreads();
        const int cl  = tid >> 3;
        const int mi0 = (tid & 7) * 8;
        const float* Ob = (const float*)smem + cl * MST;
#pragma unroll
        for (int j = 0; j < 2; j++) {
            int mi = mi0 + 4 * j;
            f32x4 s = *(const f32x4*)&Ob[mi];
            s = s + *(const f32x4*)&Ob[1 * (32 * MST) + mi];
            s = s + *(const f32x4*)&Ob[2 * (32 * MST) + mi];
            s = s + *(const f32x4*)&Ob[3 * (32 * MST) + mi];
            f32x4 li = *(const f32x4*)&Linv[mi];
            int c = ch * 128 + q * 32 + cl;
            size_t gi = ((size_t)(b * CC + c)) * NN + m0 + mi;
            f32x4 xr = *(const f32x4*)&x[gi];
            *(f32x4*)&out[gi] = s * li + xr;
        }
    }
}

extern "C" void kernel_launch(void* const* d_in, const int* in_sizes, int n_in,
                              void* d_out, int out_size, void* d_ws, size_t ws_size,
                              hipStream_t stream) {
    const float* x  = (const float*)d_in[0];
    const float* Wq = (const float*)d_in[1];
    const float* bq = (const float*)d_in[2];
    const float* Wk = (const float*)d_in[3];
    const float* bk = (const float*)d_in[4];
    const float* Wv = (const float*)d_in[5];
    const float* bv = (const float*)d_in[6];
    float* out = (float*)d_out;

    __bf16* qws = (__bf16*)d_ws;                       // B*N*32
    __bf16* kws = qws + (size_t)BB * NN * DKK;         // B*N*32
    __bf16* vws = kws + (size_t)BB * NN * DKK;         // B*C*N (tiled)

    qkv_kernel<<<dim3(128, BB), 256, 0, stream>>>(x, Wq, bq, Wk, bk, Wv, bv,
                                                  qws, kws, vws);
    attn_kernel<<<dim3(512), 256, 0, stream>>>(qws, kws, vws, x, out);
}

// Round 11
// 152.538 us; speedup vs baseline: 1.0322x; 1.0036x over previous
//
#include <hip/hip_runtime.h>
#include <hip/hip_bf16.h>
#include <math.h>

#define BB 4
#define CC 256
#define DKK 32
#define NN 4096
// 1/sqrt(32) * log2(e) — folded into q at QKV epilogue; attention uses exp2.
#define QSCALE 0.2550181864060454f

typedef __attribute__((ext_vector_type(8))) __bf16 bf16x8;
typedef __attribute__((ext_vector_type(4))) __bf16 bf16x4;
typedef __attribute__((ext_vector_type(4))) float f32x4;
typedef __attribute__((ext_vector_type(16))) float f32x16;

// ---------------------------------------------------------------------------
// Kernel 1: fused x-transpose + QKV projection (same as R10 except V layout).
// Block: 32 n x 320 o, grid (128, B) = 512 (2 blocks/CU).
// V TILED for 32x32x16 MFMA A-frags: per 32-n chunk, 8 tiles of
// [32 c][16 n]: idx = (c>>5)*1024 + (n>>4)*512 + (c&31)*16 + (n&15).
// ---------------------------------------------------------------------------
#define XST 260      // xsT row stride (bf16 elems)
#define SCRST 33     // q/k scratch row stride (fp32)

__global__ __launch_bounds__(256, 2) void qkv_kernel(
    const float* __restrict__ x,
    const float* __restrict__ Wq, const float* __restrict__ bq,
    const float* __restrict__ Wk, const float* __restrict__ bk,
    const float* __restrict__ Wv, const float* __restrict__ bv,
    __bf16* __restrict__ qws, __bf16* __restrict__ kws, __bf16* __restrict__ vws)
{
    __shared__ __align__(16) unsigned char smem[16640];
    __bf16* xsT = (__bf16*)smem;
    float*  scr = (float*)smem;

    const int tid = threadIdx.x;
    const int w   = tid >> 6;
    const int l   = tid & 63;
    const int l15 = l & 15;
    const int lq  = l >> 4;
    const int n0  = blockIdx.x * 32;
    const int b   = blockIdx.y;

    // ---- staging: thread reads float4 (4 n, 1 c), writes 4 bf16 scalars ----
    {
        const int cb = tid >> 3;
        const int nf = (tid & 7) * 4;
        const float* xp = x + ((size_t)(b * CC) + cb) * NN + n0 + nf;
#pragma unroll
        for (int r = 0; r < 8; r++) {
            float4 v = *(const float4*)(xp + (size_t)r * 32 * NN);
            int c = r * 32 + cb;
            xsT[(nf + 0) * XST + c] = (__bf16)v.x;
            xsT[(nf + 1) * XST + c] = (__bf16)v.y;
            xsT[(nf + 2) * XST + c] = (__bf16)v.z;
            xsT[(nf + 3) * XST + c] = (__bf16)v.w;
        }
    }

    const float* wp[5];
#pragma unroll
    for (int ot = 0; ot < 5; ot++) {
        int ob = 80 * w + 16 * ot;
        const float* src = (ob < 32) ? (Wq + (size_t)ob * CC)
                         : (ob < 64) ? (Wk + (size_t)(ob - 32) * CC)
                                     : (Wv + (size_t)(ob - 64) * CC);
        wp[ot] = src + (size_t)l15 * CC;
    }

    float4 wc[5][2], wn[5][2];
#pragma unroll
    for (int ot = 0; ot < 5; ot++) {
        wc[ot][0] = *(const float4*)(wp[ot] + lq * 8);
        wc[ot][1] = *(const float4*)(wp[ot] + lq * 8 + 4);
    }

    __syncthreads();

    const f32x4 zf = {0.f, 0.f, 0.f, 0.f};
    f32x4 acc[5][2];
#pragma unroll
    for (int i = 0; i < 5; i++)
#pragma unroll
        for (int j = 0; j < 2; j++) acc[i][j] = zf;

#pragma unroll
    for (int ks = 0; ks < 8; ks++) {
        if (ks < 7) {
#pragma unroll
            for (int ot = 0; ot < 5; ot++) {
                wn[ot][0] = *(const float4*)(wp[ot] + (ks + 1) * 32 + lq * 8);
                wn[ot][1] = *(const float4*)(wp[ot] + (ks + 1) * 32 + lq * 8 + 4);
            }
        }
        bf16x8 bfr[2];
#pragma unroll
        for (int nt = 0; nt < 2; nt++) {
            bf16x4 lo = *(const bf16x4*)&xsT[(nt * 16 + l15) * XST + ks * 32 + lq * 8];
            bf16x4 hi = *(const bf16x4*)&xsT[(nt * 16 + l15) * XST + ks * 32 + lq * 8 + 4];
            bfr[nt] = __builtin_shufflevector(lo, hi, 0, 1, 2, 3, 4, 5, 6, 7);
        }
#pragma unroll
        for (int ot = 0; ot < 5; ot++) {
            bf16x8 af;
            af[0] = (__bf16)wc[ot][0].x; af[1] = (__bf16)wc[ot][0].y;
            af[2] = (__bf16)wc[ot][0].z; af[3] = (__bf16)wc[ot][0].w;
            af[4] = (__bf16)wc[ot][1].x; af[5] = (__bf16)wc[ot][1].y;
            af[6] = (__bf16)wc[ot][1].z; af[7] = (__bf16)wc[ot][1].w;
#pragma unroll
            for (int nt = 0; nt < 2; nt++)
                acc[ot][nt] = __builtin_amdgcn_mfma_f32_16x16x32_bf16(af, bfr[nt], acc[ot][nt], 0, 0, 0);
        }
        if (ks < 7) {
#pragma unroll
            for (int ot = 0; ot < 5; ot++) { wc[ot][0] = wn[ot][0]; wc[ot][1] = wn[ot][1]; }
        }
    }

    __syncthreads();

    // ---- epilogue ----
    __bf16* vchunk = vws + (size_t)b * CC * NN + (size_t)(n0 >> 5) * 8192;
#pragma unroll
    for (int ot = 0; ot < 5; ot++) {
        int ob = 80 * w + ot * 16;
#pragma unroll
        for (int nt = 0; nt < 2; nt++) {
#pragma unroll
            for (int r = 0; r < 4; r++) {
                int o = ob + lq * 4 + r;
                int n = nt * 16 + l15;
                float val = acc[ot][nt][r];
                if (ob >= 64) {
                    int c = o - 64;
                    // 32x32x16 A-frag tiling: [c/32][n/16][c&31][n&15]
                    vchunk[(c >> 5) * 1024 + nt * 512 + (c & 31) * 16 + l15] =
                        (__bf16)(val + bv[c]);
                } else if (ob < 32) {
                    scr[o * SCRST + n] = (val + bq[o]) * QSCALE;
                } else {
                    scr[o * SCRST + n] = val + bk[o - 32];
                }
            }
        }
    }
    __syncthreads();
    {
        int n  = tid >> 3;
        int d0 = (tid & 7) * 4;
        bf16x4 qv, kv;
#pragma unroll
        for (int j = 0; j < 4; j++) {
            qv[j] = (__bf16)scr[(d0 + j) * SCRST + n];
            kv[j] = (__bf16)scr[(32 + d0 + j) * SCRST + n];
        }
        size_t base = ((size_t)b * NN + n0 + n) * DKK + d0;
        *(bf16x4*)&qws[base] = qv;
        *(bf16x4*)&kws[base] = kv;
    }
}

// ---------------------------------------------------------------------------
// Kernel 2: flash attention — n-split, zero-barrier main loop, PV on
// 32x32x16 MFMA (15% faster pipe, half the PV instruction count, same
// 128-AGPR accumulator). KQ stays 16x16x32 writing P[m][n] rows in LDS;
// the 32x32 B-frag read is just a different slice of the same array.
// All 8 V frags (b128, tiled layout) hoisted to iteration top.
// ---------------------------------------------------------------------------
#define PST 36                     // P row stride (bf16): 72B rows
#define MST 68                     // O-reduce row stride (dwords)
#define PWSZ (64 * PST)

__global__ __launch_bounds__(256, 2) void attn_kernel(
    const __bf16* __restrict__ qb, const __bf16* __restrict__ kb,
    const __bf16* __restrict__ vt, const float* __restrict__ x,
    float* __restrict__ out)
{
    __shared__ __align__(16) unsigned char smem[38144];
    __bf16* pw   = (__bf16*)smem + (threadIdx.x >> 6) * 2 * PWSZ;
    float*  Ls   = (float*)(smem + 36864);
    float*  Linv = (float*)(smem + 37888);

    const int tid = threadIdx.x;
    const int w   = tid >> 6;
    const int l   = tid & 63;
    const int l15 = l & 15;
    const int lq  = l >> 4;
    const int l31 = l & 31;
    const int lh  = l >> 5;

    const int beta = blockIdx.x;
    const int b    = (beta >> 1) & 3;
    const int ch   = (beta >> 3) & 1;
    const int mt   = ((beta >> 4) << 1) | (beta & 1);
    const int m0   = mt * 64;

    const __bf16* qbb = qb + (size_t)b * NN * DKK;
    const __bf16* kbb = kb + (size_t)b * NN * DKK;
    const __bf16* vtb = vt + (size_t)b * CC * NN;

    bf16x8 qa[4];
#pragma unroll
    for (int af = 0; af < 4; af++)
        qa[af] = *(const bf16x8*)(qbb + (size_t)(m0 + af * 16 + l15) * DKK + lq * 8);

    const __bf16* kstrip = kbb + (size_t)(w * 32 + l15) * DKK + lq * 8;
    // V strip: + ic*32768 + ct*1024 + ks*512; lane offset (c&31)*16 + nseg*8
    const __bf16* vstrip = vtb + (size_t)w * 8192 + (size_t)ch * 4096
                               + l31 * 16 + lh * 8;

    const f32x4  zf  = {0.f, 0.f, 0.f, 0.f};
    f32x16 acc32[2][4];
    {
        const f32x16 z16 = {0.f,0.f,0.f,0.f,0.f,0.f,0.f,0.f,
                            0.f,0.f,0.f,0.f,0.f,0.f,0.f,0.f};
#pragma unroll
        for (int i = 0; i < 2; i++)
#pragma unroll
            for (int j = 0; j < 4; j++) acc32[i][j] = z16;
    }
    float lacc[4] = {0.f, 0.f, 0.f, 0.f};

    // ---- prologue: P(0) -> buf 0 (16x16 KQ); prefetch k(1) ----
    bf16x8 kA0 = *(const bf16x8*)kstrip;
    bf16x8 kA1 = *(const bf16x8*)(kstrip + 16 * DKK);
#pragma unroll
    for (int af = 0; af < 4; af++) {
        f32x4 e0 = __builtin_amdgcn_mfma_f32_16x16x32_bf16(kA0, qa[af], zf, 0, 0, 0);
        f32x4 e1 = __builtin_amdgcn_mfma_f32_16x16x32_bf16(kA1, qa[af], zf, 0, 0, 0);
        bf16x4 p0, p1;
#pragma unroll
        for (int r = 0; r < 4; r++) {
            float v0 = __builtin_amdgcn_exp2f(e0[r]); lacc[af] += v0; p0[r] = (__bf16)v0;
            float v1 = __builtin_amdgcn_exp2f(e1[r]); lacc[af] += v1; p1[r] = (__bf16)v1;
        }
        *(bf16x4*)&pw[(af * 16 + l15) * PST + lq * 4]      = p0;
        *(bf16x4*)&pw[(af * 16 + l15) * PST + 16 + lq * 4] = p1;
    }
    kA0 = *(const bf16x8*)(kstrip + (size_t)128 * DKK);
    kA1 = *(const bf16x8*)(kstrip + (size_t)144 * DKK);

    // ---- main loop: zero barriers, intra-wave only ----
#pragma unroll 2
    for (int ic = 0; ic < 31; ic++) {
        const int cur = ic & 1;
        const __bf16* vch = vstrip + (size_t)ic * 32768;

        // all 8 V A-frags up front (b128 each, ~full-iteration latency cover)
        bf16x8 vf[4][2];
#pragma unroll
        for (int ct = 0; ct < 4; ct++) {
            vf[ct][0] = *(const bf16x8*)(vch + ct * 1024);
            vf[ct][1] = *(const bf16x8*)(vch + ct * 1024 + 512);
        }

        // P B-frags for 32x32x16: B[k=n][m]: m=l31(+32*mt2), n=ks*16+lh*8+j
        bf16x8 pf[2][2];
#pragma unroll
        for (int mt2 = 0; mt2 < 2; mt2++)
#pragma unroll
            for (int ks = 0; ks < 2; ks++) {
                const __bf16* pr = &pw[cur * PWSZ + (mt2 * 32 + l31) * PST + ks * 16 + lh * 8];
                bf16x4 plo = *(const bf16x4*)pr;
                bf16x4 phi = *(const bf16x4*)(pr + 4);
                pf[mt2][ks] = __builtin_shufflevector(plo, phi, 0, 1, 2, 3, 4, 5, 6, 7);
            }

        // KQ(ic+1) + exp2 into the other wave-private buffer (16x16)
#pragma unroll
        for (int af = 0; af < 4; af++) {
            f32x4 e0 = __builtin_amdgcn_mfma_f32_16x16x32_bf16(kA0, qa[af], zf, 0, 0, 0);
            f32x4 e1 = __builtin_amdgcn_mfma_f32_16x16x32_bf16(kA1, qa[af], zf, 0, 0, 0);
            bf16x4 p0, p1;
#pragma unroll
            for (int r = 0; r < 4; r++) {
                float v0 = __builtin_amdgcn_exp2f(e0[r]); lacc[af] += v0; p0[r] = (__bf16)v0;
                float v1 = __builtin_amdgcn_exp2f(e1[r]); lacc[af] += v1; p1[r] = (__bf16)v1;
            }
            *(bf16x4*)&pw[(cur ^ 1) * PWSZ + (af * 16 + l15) * PST + lq * 4]      = p0;
            *(bf16x4*)&pw[(cur ^ 1) * PWSZ + (af * 16 + l15) * PST + 16 + lq * 4] = p1;
        }
        kA0 = *(const bf16x8*)(kstrip + (size_t)(ic + 2) * 128 * DKK);
        kA1 = *(const bf16x8*)(kstrip + (size_t)((ic + 2) * 128 + 16) * DKK);

        // PV(ic): D[c][m] += V[c][n] P[n][m], 16 MFMAs of 32x32x16
#pragma unroll
        for (int mt2 = 0; mt2 < 2; mt2++)
#pragma unroll
            for (int ct = 0; ct < 4; ct++) {
                acc32[mt2][ct] = __builtin_amdgcn_mfma_f32_32x32x16_bf16(
                    vf[ct][0], pf[mt2][0], acc32[mt2][ct], 0, 0, 0);
                acc32[mt2][ct] = __builtin_amdgcn_mfma_f32_32x32x16_bf16(
                    vf[ct][1], pf[mt2][1], acc32[mt2][ct], 0, 0, 0);
            }
    }

    // ---- peel: PV(31) ----
    {
        const __bf16* vch = vstrip + (size_t)31 * 32768;
        bf16x8 vf[4][2];
#pragma unroll
        for (int ct = 0; ct < 4; ct++) {
            vf[ct][0] = *(const bf16x8*)(vch + ct * 1024);
            vf[ct][1] = *(const bf16x8*)(vch + ct * 1024 + 512);
        }
        bf16x8 pf[2][2];
#pragma unroll
        for (int mt2 = 0; mt2 < 2; mt2++)
#pragma unroll
            for (int ks = 0; ks < 2; ks++) {
                const __bf16* pr = &pw[(31 & 1) * PWSZ + (mt2 * 32 + l31) * PST + ks * 16 + lh * 8];
                bf16x4 plo = *(const bf16x4*)pr;
                bf16x4 phi = *(const bf16x4*)(pr + 4);
                pf[mt2][ks] = __builtin_shufflevector(plo, phi, 0, 1, 2, 3, 4, 5, 6, 7);
            }
#pragma unroll
        for (int mt2 = 0; mt2 < 2; mt2++)
#pragma unroll
            for (int ct = 0; ct < 4; ct++) {
                acc32[mt2][ct] = __builtin_amdgcn_mfma_f32_32x32x16_bf16(
                    vf[ct][0], pf[mt2][0], acc32[mt2][ct], 0, 0, 0);
                acc32[mt2][ct] = __builtin_amdgcn_mfma_f32_32x32x16_bf16(
                    vf[ct][1], pf[mt2][1], acc32[mt2][ct], 0, 0, 0);
            }
    }

    // ---- l: intra-wave reduce, publish per-wave partials ----
#pragma unroll
    for (int af = 0; af < 4; af++) {
        lacc[af] += __shfl_xor(lacc[af], 16, 64);
        lacc[af] += __shfl_xor(lacc[af], 32, 64);
    }
    if (lq == 0) {
#pragma unroll
        for (int af = 0; af < 4; af++) Ls[w * 64 + af * 16 + l15] = lacc[af];
    }
    __syncthreads();
    if (tid < 64)
        Linv[tid] = 1.0f / (Ls[tid] + Ls[64 + tid] + Ls[128 + tid] + Ls[192 + tid]);

    // ---- epilogue: cross-wave O reduce in 4 quarters of 32 c ----
    // acc32 D-layout: col m = l31 (+32*mt2); row c = (reg&3)+8*(reg>>2)+4*lh
    float* Ored = (float*)smem + w * (32 * MST);
#pragma unroll
    for (int q = 0; q < 4; q++) {
        if (q > 0) __syncthreads();
#pragma unroll
        for (int mt2 = 0; mt2 < 2; mt2++) {
#pragma unroll
            for (int reg = 0; reg < 16; reg++) {
                int row = (reg & 3) + 8 * (reg >> 2) + 4 * lh;
                Ored[row * MST + mt2 * 32 + l31] = acc32[mt2][q][reg];
            }
        }
        __syncthreads();
        const int cl  = tid >> 3;
        const int mi0 = (tid & 7) * 8;
        const float* Ob = (const float*)smem + cl * MST;
#pragma unroll
        for (int j = 0; j < 2; j++) {
            int mi = mi0 + 4 * j;
            f32x4 s = *(const f32x4*)&Ob[mi];
            s = s + *(const f32x4*)&Ob[1 * (32 * MST) + mi];
            s = s + *(const f32x4*)&Ob[2 * (32 * MST) + mi];
            s = s + *(const f32x4*)&Ob[3 * (32 * MST) + mi];
            f32x4 li = *(const f32x4*)&Linv[mi];
            int c = ch * 128 + q * 32 + cl;
            size_t gi = ((size_t)(b * CC + c)) * NN + m0 + mi;
            f32x4 xr = *(const f32x4*)&x[gi];
            *(f32x4*)&out[gi] = s * li + xr;
        }
    }
}

extern "C" void kernel_launch(void* const* d_in, const int* in_sizes, int n_in,
                              void* d_out, int out_size, void* d_ws, size_t ws_size,
                              hipStream_t stream) {
    const float* x  = (const float*)d_in[0];
    const float* Wq = (const float*)d_in[1];
    const float* bq = (const float*)d_in[2];
    const float* Wk = (const float*)d_in[3];
    const float* bk = (const float*)d_in[4];
    const float* Wv = (const float*)d_in[5];
    const float* bv = (const float*)d_in[6];
    float* out = (float*)d_out;

    __bf16* qws = (__bf16*)d_ws;                       // B*N*32
    __bf16* kws = qws + (size_t)BB * NN * DKK;         // B*N*32
    __bf16* vws = kws + (size_t)BB * NN * DKK;         // B*C*N (tiled 32x16)

    qkv_kernel<<<dim3(128, BB), 256, 0, stream>>>(x, Wq, bq, Wk, bk, Wv, bv,
                                                  qws, kws, vws);
    attn_kernel<<<dim3(512), 256, 0, stream>>>(qws, kws, vws, x, out);
}